// Round 1
// baseline (1513.557 us; speedup 1.0000x reference)
//
#include <hip/hip_runtime.h>

typedef unsigned short u16;
typedef unsigned int u32;
typedef __attribute__((ext_vector_type(8))) short bf16x8;
typedef __attribute__((ext_vector_type(4))) float f32x4;

__device__ __forceinline__ u16 f2bf(float f) {
  u32 u = __builtin_bit_cast(u32, f);
  u += 0x7FFFu + ((u >> 16) & 1u);
  return (u16)(u >> 16);
}
__device__ __forceinline__ float bf2f(u16 h) {
  u32 u = ((u32)h) << 16;
  return __builtin_bit_cast(float, u);
}
__device__ __forceinline__ u32 packbf(float a, float b) {
  return (u32)f2bf(a) | ((u32)f2bf(b) << 16);
}
__device__ __forceinline__ void gload_lds16(const u16* g, u16* l) {
  __builtin_amdgcn_global_load_lds((const __attribute__((address_space(1))) u32*)g,
                                   (__attribute__((address_space(3))) u32*)l, 16, 0, 0);
}

// ---------------- LayerNorm: fp32 x [4096][2048] -> bf16 xn ----------------
__global__ __launch_bounds__(256) void ln_kernel(const float* __restrict__ x,
                                                 const float* __restrict__ gamma,
                                                 u16* __restrict__ xn) {
  int row = blockIdx.x;
  int t = threadIdx.x;
  const float4* xr4 = (const float4*)(x + (size_t)row * 2048);
  float4 a = xr4[t], b = xr4[t + 256];
  float s = a.x + a.y + a.z + a.w + b.x + b.y + b.z + b.w;
  float ss = a.x*a.x + a.y*a.y + a.z*a.z + a.w*a.w
           + b.x*b.x + b.y*b.y + b.z*b.z + b.w*b.w;
#pragma unroll
  for (int off = 32; off; off >>= 1) { s += __shfl_xor(s, off); ss += __shfl_xor(ss, off); }
  __shared__ float red[16];
  int w = t >> 6, lane = t & 63;
  if (lane == 0) { red[w] = s; red[8 + w] = ss; }
  __syncthreads();
  s = red[0] + red[1] + red[2] + red[3];
  ss = red[8] + red[9] + red[10] + red[11];
  float mu = s * (1.0f/2048.0f);
  float var = ss * (1.0f/2048.0f) - mu*mu;
  float rs = rsqrtf(var + 1e-5f);
  const float4* g4 = (const float4*)gamma;
  float4 ga = g4[t], gb = g4[t + 256];
  u16* orow = xn + (size_t)row * 2048;
  ushort4 o0;
  o0.x = f2bf((a.x - mu) * rs * ga.x);
  o0.y = f2bf((a.y - mu) * rs * ga.y);
  o0.z = f2bf((a.z - mu) * rs * ga.z);
  o0.w = f2bf((a.w - mu) * rs * ga.w);
  *(ushort4*)(orow + t*4) = o0;
  ushort4 o1;
  o1.x = f2bf((b.x - mu) * rs * gb.x);
  o1.y = f2bf((b.y - mu) * rs * gb.y);
  o1.z = f2bf((b.z - mu) * rs * gb.z);
  o1.w = f2bf((b.w - mu) * rs * gb.w);
  *(ushort4*)(orow + (t+256)*4) = o1;
}

// ------- transpose+convert: dst[c][r+doff] (bf16, ld=dld) = src[r][c] (fp32, ld=sld)
__global__ __launch_bounds__(256) void tconv_kernel(const float* __restrict__ src,
                                                    u16* __restrict__ dst,
                                                    int sld, int dld, int doff) {
  __shared__ u16 tile[64][72];
  int c0 = blockIdx.x * 64, r0 = blockIdx.y * 64;
  int t = threadIdx.x;
#pragma unroll
  for (int p = 0; p < 4; ++p) {
    int cc = t + 256*p;
    int r = cc >> 4, c4 = (cc & 15) * 4;
    float4 v = *(const float4*)(src + (size_t)(r0 + r) * sld + c0 + c4);
    ushort4 o; o.x = f2bf(v.x); o.y = f2bf(v.y); o.z = f2bf(v.z); o.w = f2bf(v.w);
    *(ushort4*)&tile[r][c4] = o;
  }
  __syncthreads();
#pragma unroll
  for (int p = 0; p < 2; ++p) {
    int cc = t + 256*p;
    int dr = cc >> 3, s8 = (cc & 7) * 8;
    bf16x8 vv;
#pragma unroll
    for (int e = 0; e < 8; ++e) vv[e] = (short)tile[s8 + e][dr];
    *(bf16x8*)(dst + (size_t)(c0 + dr) * dld + doff + r0 + s8) = vv;
  }
}

// ---------------- GEMM: C[M,N] = A[M,K] * B[K,N], B given as BT[N,K] -------
// 128x128 tile, 4 waves (2x2), BK=32, global_load_lds staging.
// MODE 1: bf16 out with qkv/acat/gate routing (fused projection)
// MODE 2: fp32 out, ldc=2048 (final output)
template<int MODE>
__global__ __launch_bounds__(256) void gemm_bt(const u16* __restrict__ A,
                                               const u16* __restrict__ BT,
                                               int K,
                                               float* __restrict__ outf,
                                               u16* __restrict__ dq,
                                               u16* __restrict__ d1,
                                               u16* __restrict__ d2) {
  __shared__ u16 As[128*32];
  __shared__ u16 Bs[128*32];
  int t = threadIdx.x;
  int lane = t & 63;
  int w = t >> 6;
  int wr = w >> 1, wc = w & 1;
  int bm = blockIdx.x * 128;
  int bn = blockIdx.y * 128;
  int srow = t >> 2, sch = (t & 3) * 8;
  const u16* Ag = A + (size_t)(bm + srow) * K + sch;
  const u16* Bg = BT + (size_t)(bn + srow) * K + sch;
  int wu = __builtin_amdgcn_readfirstlane(w);
  u16* AsW = As + wu * 512;
  u16* BsW = Bs + wu * 512;
  int lr = lane & 15, lk8 = (lane >> 4) * 8;
  const u16* pa = As + (wr*64 + lr)*32 + lk8;
  const u16* pb = Bs + (wc*64 + lr)*32 + lk8;
  size_t rj = (size_t)64 * K;
  f32x4 acc[4][4];
#pragma unroll
  for (int i = 0; i < 4; ++i)
#pragma unroll
    for (int jn = 0; jn < 4; ++jn) acc[i][jn] = (f32x4){0.f,0.f,0.f,0.f};
  for (int k0 = 0; k0 < K; k0 += 32) {
    gload_lds16(Ag + k0, AsW);
    gload_lds16(Ag + k0 + rj, AsW + 2048);
    gload_lds16(Bg + k0, BsW);
    gload_lds16(Bg + k0 + rj, BsW + 2048);
    __syncthreads();
    bf16x8 af[4], bfr[4];
#pragma unroll
    for (int mi = 0; mi < 4; ++mi) af[mi] = *(const bf16x8*)(pa + mi*512);
#pragma unroll
    for (int ni = 0; ni < 4; ++ni) bfr[ni] = *(const bf16x8*)(pb + ni*512);
#pragma unroll
    for (int mi = 0; mi < 4; ++mi)
#pragma unroll
      for (int ni = 0; ni < 4; ++ni)
        acc[mi][ni] = __builtin_amdgcn_mfma_f32_16x16x32_bf16(af[mi], bfr[ni], acc[mi][ni], 0, 0, 0);
    __syncthreads();
  }
  int r0 = bm + wr*64 + (lane >> 4)*4;
  if (MODE == 2) {
    int c0 = bn + wc*64 + lr;
#pragma unroll
    for (int mi = 0; mi < 4; ++mi)
#pragma unroll
      for (int i = 0; i < 4; ++i) {
        float* orow = outf + (size_t)(r0 + mi*16 + i) * 2048 + c0;
#pragma unroll
        for (int ni = 0; ni < 4; ++ni) orow[ni*16] = acc[mi][ni][i];
      }
  } else {
    int nt = blockIdx.y;
    u16* dst; int ldc, col0;
    if (nt < 18)      { dst = dq; ldc = 2304;  col0 = nt*128; }
    else if (nt < 82) { dst = d1; ldc = 10240; col0 = 2048 + (nt-18)*128; }
    else              { dst = d2; ldc = 8192;  col0 = (nt-82)*128; }
    int c0 = col0 + wc*64 + lr;
#pragma unroll
    for (int mi = 0; mi < 4; ++mi)
#pragma unroll
      for (int i = 0; i < 4; ++i) {
        u16* orow = dst + (size_t)(r0 + mi*16 + i) * ldc + c0;
#pragma unroll
        for (int ni = 0; ni < 4; ++ni) orow[ni*16] = f2bf(acc[mi][ni][i]);
      }
  }
}

// ---------------- RoPE (xpos) on q (scaled) and k (inverse scale) ----------
__global__ __launch_bounds__(256) void rope_kernel(const u16* __restrict__ qkv,
                                                   u16* __restrict__ qr,
                                                   u16* __restrict__ kr) {
  int row = blockIdx.x;                 // b*2048 + j
  int b = row >> 11, j = row & 2047;
  const u16* src = qkv + (size_t)row * 2304;
  int t = threadIdx.x;
  float power = (float)(j - 1024) * (1.0f/512.0f);
  const float NL2 = -0.2076205059304703f; // -log2(10000)/64
#pragma unroll
  for (int p = 0; p < 4; ++p) {
    int idx = t + 256*p;
    int h = idx >> 6, dv = idx & 63;
    float fr = (float)j * exp2f((float)dv * NL2);
    float c = cosf(fr), s = sinf(fr);
    float bs = ((float)(2*dv) + 51.2f) * (1.0f/179.2f);
    float sc = exp2f(power * log2f(bs)) * 0.08838834764831845f; // * dim_head^-0.5
    float x1 = bf2f(src[h*128 + dv]);
    float x2 = bf2f(src[h*128 + dv + 64]);
    u16* qo = qr + (((size_t)(b*16 + h))*2048 + j)*128;
    qo[dv]      = f2bf((x1*c - x2*s) * sc);
    qo[dv + 64] = f2bf((x2*c + x1*s) * sc);
  }
  if (t < 64) {
    int dv = t;
    float fr = (float)j * exp2f((float)dv * NL2);
    float c = cosf(fr), s = sinf(fr);
    float bs = ((float)(2*dv) + 51.2f) * (1.0f/179.2f);
    float sc = exp2f(-power * log2f(bs));  // 1/scale
    float x1 = bf2f(src[2048 + dv]);
    float x2 = bf2f(src[2048 + dv + 64]);
    u16* ko = kr + ((size_t)b*2048 + j)*128;
    ko[dv]      = f2bf((x1*c - x2*s) * sc);
    ko[dv + 64] = f2bf((x2*c + x1*s) * sc);
  }
}

// ---------------- V transpose: qkv v-part [b][n][128] -> vT [b][128][2048] --
__global__ __launch_bounds__(256) void vtrans_kernel(const u16* __restrict__ qkv,
                                                     u16* __restrict__ vT) {
  __shared__ u16 tile[64][136];
  int j0 = blockIdx.x * 64, b = blockIdx.y;
  int t = threadIdx.x;
#pragma unroll
  for (int p = 0; p < 4; ++p) {
    int cc = t + 256*p;
    int r = cc >> 4, c8 = (cc & 15) * 8;
    bf16x8 v = *(const bf16x8*)(qkv + (size_t)(b*2048 + j0 + r) * 2304 + 2176 + c8);
#pragma unroll
    for (int e = 0; e < 8; ++e) tile[r][c8 + e] = (u16)v[e];
  }
  __syncthreads();
#pragma unroll
  for (int p = 0; p < 4; ++p) {
    int cc = t + 256*p;
    int dv = cc >> 3, s8 = (cc & 7) * 8;
    bf16x8 o;
#pragma unroll
    for (int e = 0; e < 8; ++e) o[e] = (short)tile[s8 + e][dv];
    *(bf16x8*)(vT + (size_t)(b*128 + dv)*2048 + j0 + s8) = o;
  }
}

// ---------------- Flash attention, causal, MQA (1 kv head) -----------------
// Swapped QK^T: S^T = mfma(K, Q) so each lane owns one q row (q = lane&15).
__global__ __launch_bounds__(256) void attn_kernel(const u16* __restrict__ qr,
                                                   const u16* __restrict__ kr,
                                                   const u16* __restrict__ vT,
                                                   u16* __restrict__ acat) {
  int b = blockIdx.z, h = blockIdx.y;
  int t = threadIdx.x;
  int w = t >> 6, lane = t & 63;
  int lr = lane & 15, g = lane >> 4;
  int lk8 = g * 8;
  int q_base = blockIdx.x * 64 + w * 16;
  int q_glob = q_base + lr;
  const u16* qrow = qr + (((size_t)(b*16 + h))*2048 + q_base + lr)*128 + lk8;
  bf16x8 qf[4];
#pragma unroll
  for (int di = 0; di < 4; ++di) qf[di] = *(const bf16x8*)(qrow + di*32);
  const u16* kbase = kr + (size_t)b * 2048 * 128;
  const u16* vbase = vT + (size_t)b * 128 * 2048 + (size_t)lr * 2048 + lk8;
  float m = -1e30f, ssum = 0.f;
  f32x4 o[8];
#pragma unroll
  for (int f = 0; f < 8; ++f) o[f] = (f32x4){0.f,0.f,0.f,0.f};
  int ktiles = (q_base + 15)/32 + 1;
  for (int kt = 0; kt < ktiles; ++kt) {
    int k0 = kt * 32;
    const u16* kp = kbase + (size_t)(k0 + lr) * 128 + lk8;
    f32x4 s0 = (f32x4){0.f,0.f,0.f,0.f}, s1 = (f32x4){0.f,0.f,0.f,0.f};
#pragma unroll
    for (int di = 0; di < 4; ++di) {
      bf16x8 kf0 = *(const bf16x8*)(kp + di*32);
      bf16x8 kf1 = *(const bf16x8*)(kp + 2048 + di*32);   // +16 rows
      s0 = __builtin_amdgcn_mfma_f32_16x16x32_bf16(kf0, qf[di], s0, 0, 0, 0);
      s1 = __builtin_amdgcn_mfma_f32_16x16x32_bf16(kf1, qf[di], s1, 0, 0, 0);
    }
    float sv[8];
#pragma unroll
    for (int i = 0; i < 4; ++i) { sv[i] = s0[i]; sv[4+i] = s1[i]; }
    int kb = k0 + g*4;
#pragma unroll
    for (int e = 0; e < 8; ++e) {
      int kg = kb + (e >> 2)*16 + (e & 3);
      sv[e] = (kg > q_glob) ? -1e30f : sv[e];
    }
    float mt = sv[0];
#pragma unroll
    for (int e = 1; e < 8; ++e) mt = fmaxf(mt, sv[e]);
    mt = fmaxf(mt, __shfl_xor(mt, 16));
    mt = fmaxf(mt, __shfl_xor(mt, 32));
    float mnew = fmaxf(m, mt);
    float corr = __expf(m - mnew);
    float pv[8];
    float ps = 0.f;
#pragma unroll
    for (int e = 0; e < 8; ++e) { pv[e] = __expf(sv[e] - mnew); ps += pv[e]; }
    ps += __shfl_xor(ps, 16);
    ps += __shfl_xor(ps, 32);
    ssum = ssum * corr + ps;
    m = mnew;
#pragma unroll
    for (int f = 0; f < 8; ++f) o[f] = o[f] * corr;
    // redistribute P (lane holds k = g*4+i and 16+g*4+i) to B-operand layout (k = g*8+j)
    u32 u01 = packbf(pv[0], pv[1]);
    u32 u23 = packbf(pv[2], pv[3]);
    u32 u45 = packbf(pv[4], pv[5]);
    u32 u67 = packbf(pv[6], pv[7]);
    int srcA = ((2*g) & 3)*16 + lr;
    int srcB = ((2*g + 1) & 3)*16 + lr;
    u32 a01 = __shfl(u01, srcA), a23 = __shfl(u23, srcA);
    u32 a45 = __shfl(u45, srcA), a67 = __shfl(u67, srcA);
    u32 b01 = __shfl(u01, srcB), b23 = __shfl(u23, srcB);
    u32 b45 = __shfl(u45, srcB), b67 = __shfl(u67, srcB);
    bool hi = g >= 2;
    union { u32 u[4]; bf16x8 v; } pu;
    pu.u[0] = hi ? a45 : a01;
    pu.u[1] = hi ? a67 : a23;
    pu.u[2] = hi ? b45 : b01;
    pu.u[3] = hi ? b67 : b23;
    bf16x8 pf = pu.v;
    const u16* vp = vbase + k0;
#pragma unroll
    for (int f = 0; f < 8; ++f) {
      bf16x8 vf = *(const bf16x8*)(vp + (size_t)f * 16 * 2048);
      o[f] = __builtin_amdgcn_mfma_f32_16x16x32_bf16(vf, pf, o[f], 0, 0, 0);
    }
  }
  float inv = 1.0f / ssum;
  u16* orow = acat + ((size_t)(b*2048 + q_base + lr)) * 10240 + h*128 + g*4;
#pragma unroll
  for (int f = 0; f < 8; ++f) {
    ushort4 st;
    st.x = f2bf(o[f][0] * inv);
    st.y = f2bf(o[f][1] * inv);
    st.z = f2bf(o[f][2] * inv);
    st.w = f2bf(o[f][3] * inv);
    *(ushort4*)(orow + f*16) = st;
  }
}

// ---------------- SwiGLU in place: acat[m][2048+j] *= silu(gate[m][j]) -----
__global__ __launch_bounds__(256) void silu_kernel(const u16* __restrict__ gate,
                                                   u16* __restrict__ acat) {
  int mrow = blockIdx.y;
  int c8 = (blockIdx.x * 256 + threadIdx.x) * 8;
  const u16* gp = gate + (size_t)mrow * 8192 + c8;
  u16* ap = acat + (size_t)mrow * 10240 + 2048 + c8;
  bf16x8 gv = *(const bf16x8*)gp;
  bf16x8 xv = *(const bf16x8*)ap;
  bf16x8 ov;
#pragma unroll
  for (int e = 0; e < 8; ++e) {
    float g = bf2f((u16)gv[e]);
    float x = bf2f((u16)xv[e]);
    float sil = g / (1.0f + __expf(-g));
    ov[e] = (short)f2bf(sil * x);
  }
  *(bf16x8*)ap = ov;
}

extern "C" void kernel_launch(void* const* d_in, const int* in_sizes, int n_in,
                              void* d_out, int out_size, void* d_ws, size_t ws_size,
                              hipStream_t stream) {
  (void)in_sizes; (void)n_in; (void)out_size; (void)ws_size;
  const float* x     = (const float*)d_in[0];
  const float* gamma = (const float*)d_in[1];
  const float* wf    = (const float*)d_in[2];
  const float* wa    = (const float*)d_in[3];
  const float* wff   = (const float*)d_in[4];
  float* out = (float*)d_out;
  char* ws = (char*)d_ws;
  size_t off = 0;
  auto alloc = [&](size_t elems) -> u16* {
    u16* p = (u16*)(ws + off);
    off += (elems * 2 + 255) & ~(size_t)255;
    return p;
  };
  u16* xn    = alloc((size_t)4096*2048);     // LN output
  u16* wfT   = alloc((size_t)18688*2048);    // w_fused^T bf16
  u16* wcatT = alloc((size_t)2048*10240);    // [w_attn_out; w_ff_out]^T bf16
  u16* qkv   = alloc((size_t)4096*2304);     // q|k|v projection
  u16* gate  = alloc((size_t)4096*8192);     // ff_gate
  u16* acat  = alloc((size_t)4096*10240);    // [attn_out_heads | ff_x (silu'd)]
  u16* q_r   = alloc((size_t)2*16*2048*128); // q after rope, [b,h,n,d]
  u16* k_r   = alloc((size_t)2*2048*128);    // k after rope
  u16* vT    = alloc((size_t)2*128*2048);    // v transposed [b,d,n]

  ln_kernel<<<4096, 256, 0, stream>>>(x, gamma, xn);
  tconv_kernel<<<dim3(292, 32), 256, 0, stream>>>(wf, wfT, 18688, 2048, 0);
  tconv_kernel<<<dim3(32, 32), 256, 0, stream>>>(wa, wcatT, 2048, 10240, 0);
  tconv_kernel<<<dim3(32, 128), 256, 0, stream>>>(wff, wcatT, 2048, 10240, 2048);
  gemm_bt<1><<<dim3(32, 146), 256, 0, stream>>>(xn, wfT, 2048, nullptr, qkv, acat, gate);
  rope_kernel<<<4096, 256, 0, stream>>>(qkv, q_r, k_r);
  vtrans_kernel<<<dim3(32, 2), 256, 0, stream>>>(qkv, vT);
  attn_kernel<<<dim3(32, 16, 2), 256, 0, stream>>>(q_r, k_r, vT, acat);
  silu_kernel<<<dim3(4, 4096), 256, 0, stream>>>(gate, acat);
  gemm_bt<2><<<dim3(32, 16), 256, 0, stream>>>(acat, wcatT, 10240, out, nullptr, nullptr, nullptr);
}